// Round 12
// baseline (72.035 us; speedup 1.0000x reference)
//
#include <hip/hip_runtime.h>
#include <hip/hip_bf16.h>
#include <stdint.h>
#include <math.h>

#define H_HT 26
#define W_HT 122
#define NPIX (H_HT * W_HT)   // 3172
#define NA 60
#define NR 125
#define NB 32
#define NC 4
#define NBC (NB * NC)        // 128
#define PH 288
#define PW 800
#define NSPLIT 16            // rho splits per angle; wave bins r = q*4+w + 64t
#define PIX_PT 13            // ceil(3172/256) pixels per thread in csr

#define GT_BLKS ((NPIX + 1) / 2)         // 1586 transpose-gather blocks
#define ZERO_BLKS 4

// ---- workspace layout (bytes) ----
#define WS_OFF   190336                    // int32 [60*126]          30240
#define WS_LIST  220608                    // uint16[60*3172]        380640
#define WS_PREDT 601280                    // float [3172*128]      1624064
#define WS_PVP   2225344                   // u64   [128*60]          61440

// ---------------- Kernel A: fused setup -------------------------------------
__global__ __launch_bounds__(256) void setup(const float* __restrict__ vote,
                                             const float* __restrict__ pred,
                                             int* __restrict__ off,
                                             uint16_t* __restrict__ list,
                                             float* __restrict__ pred_T,
                                             unsigned long long* __restrict__ pvp) {
    const int tid = threadIdx.x;
    if (blockIdx.x < NA) {
        const int a = blockIdx.x;
        __shared__ int s_cnt[NR];
        __shared__ int sc[2][NR];
        __shared__ int s_pre[NR + 1];
        __shared__ int s_cur[NR];

        float sn, cs;
        __sincosf((float)(a * 3) * 0.017453292519943295f, &sn, &cs);

        int  rloc[PIX_PT];
        bool grd[PIX_PT];
#pragma unroll
        for (int k = 0; k < PIX_PT; ++k) {
            int p = tid + k * 256;
            rloc[k] = 0; grd[k] = false;
            if (p < NPIX) {
                int h = p / W_HT;
                int w = p - h * W_HT;
                float xs = (float)w - 60.5f;
                float ys = (float)h - 12.5f;
                float rho = xs * cs + ys * sn;
                int r = (int)rintf(rho) + NR / 2;
                r = r < 0 ? 0 : (r > NR - 1 ? NR - 1 : r);
                rloc[k] = r;
                grd[k] = fabsf(rho - floorf(rho) - 0.5f) < 1e-3f;
            }
        }
        float vv[PIX_PT];
#pragma unroll
        for (int k = 0; k < PIX_PT; ++k) {
            int p = tid + k * 256;
            vv[k] = 1.0f;
            if (p < NPIX && grd[k])
                vv[k] = vote[(size_t)(p * NA + a) * NR + rloc[k]];
        }
#pragma unroll
        for (int k = 0; k < PIX_PT; ++k) {
            int p = tid + k * 256;
            if (p < NPIX && grd[k] && vv[k] == 0.0f) {
                const float* vrow = vote + (size_t)(p * NA + a) * NR;
                int r = rloc[k];
                if (r + 1 < NR && vrow[r + 1] != 0.0f) r = r + 1;
                else if (r - 1 >= 0 && vrow[r - 1] != 0.0f) r = r - 1;
                else {
                    for (int r2 = 0; r2 < NR; ++r2)
                        if (vrow[r2] != 0.0f) { r = r2; break; }
                }
                rloc[k] = r;
            }
        }
        for (int i = tid; i < NR; i += 256) s_cnt[i] = 0;
        __syncthreads();
#pragma unroll
        for (int k = 0; k < PIX_PT; ++k) {
            int p = tid + k * 256;
            if (p < NPIX) atomicAdd(&s_cnt[rloc[k]], 1);
        }
        __syncthreads();
        if (tid < NR) sc[0][tid] = s_cnt[tid];
        __syncthreads();
        int pin = 0;
        for (int d = 1; d < NR; d <<= 1) {
            if (tid < NR) {
                int v = sc[pin][tid];
                if (tid >= d) v += sc[pin][tid - d];
                sc[pin ^ 1][tid] = v;
            }
            __syncthreads();
            pin ^= 1;
        }
        if (tid == 0) s_pre[0] = 0;
        if (tid < NR) s_pre[tid + 1] = sc[pin][tid];
        __syncthreads();
        for (int r = tid; r < NR + 1; r += 256) off[a * (NR + 1) + r] = s_pre[r];
        for (int r = tid; r < NR; r += 256) s_cur[r] = s_pre[r];
        __syncthreads();
#pragma unroll
        for (int k = 0; k < PIX_PT; ++k) {
            int p = tid + k * 256;
            if (p < NPIX) {
                int slot = atomicAdd(&s_cur[rloc[k]], 1);
                list[a * NPIX + slot] = (uint16_t)p;
            }
        }
    } else if (blockIdx.x < NA + GT_BLKS) {
        const int bidx = blockIdx.x - NA;
        const int p  = bidx * 2 + (tid >> 7);
        const int bc = tid & 127;
        if (p < NPIX) {
            const float C1 = (float)(288.0 / 26.0);
            const float C2 = (float)(800.0 / 122.0);
            int h = p / W_HT;
            int w = p - h * W_HT;
            int hi = (int)floorf((float)h * C1);
            int wi = (int)floorf((float)w * C2);
            pred_T[p * NBC + bc] = pred[((size_t)bc * PH + hi) * PW + wi];
        }
    } else {
        int i0 = (blockIdx.x - NA - GT_BLKS) * 256 + tid;
        for (int i = i0; i < NA * NBC; i += ZERO_BLKS * 256) pvp[i] = 0ull;
    }
}

// ---------------- Kernel B: transposed hough (R10 version, unchanged) -------
__global__ __launch_bounds__(256) void hough_T4(const float* __restrict__ pred_T,
                                                const int* __restrict__ off,
                                                const uint16_t* __restrict__ list,
                                                unsigned long long* __restrict__ pvp) {
    __shared__ uint16_t s_list[NPIX];    // 6344 B
    __shared__ int      s_off[NR + 1];
    __shared__ float    s_v0[4][64], s_v1[4][64];
    __shared__ int      s_i0[4][64], s_i1[4][64];

    const int blk  = blockIdx.x;
    const int a    = blk / NSPLIT;
    const int q    = blk - a * NSPLIT;
    const int tid  = threadIdx.x;
    const int w    = tid >> 6;
    const int lane = tid & 63;

    {   // stage full angle list (coalesced as uint32) + offsets
        const uint32_t* src = reinterpret_cast<const uint32_t*>(list + a * NPIX);
        uint32_t* dst = reinterpret_cast<uint32_t*>(s_list);
        for (int i = tid; i < NPIX / 2; i += 256) dst[i] = src[i];
        for (int r = tid; r < NR + 1; r += 256) s_off[r] = off[a * (NR + 1) + r];
    }
    __syncthreads();

    const float2* pT2 = reinterpret_cast<const float2*>(pred_T);
    float bv0 = -1.0f, bv1 = -1.0f; int bi0 = 0x7fffffff, bi1 = 0x7fffffff;
    for (int r = q * 4 + w; r < NR; r += 64) {
        int o0 = s_off[r];
        int o1 = s_off[r + 1];
        float x0 = 0, x1 = 0, x2 = 0, x3 = 0, x4 = 0, x5 = 0, x6 = 0, x7 = 0;
        float y0 = 0, y1 = 0, y2 = 0, y3 = 0, y4 = 0, y5 = 0, y6 = 0, y7 = 0;
        int j = o0;
        for (; j + 8 <= o1; j += 8) {
            float2 v0 = pT2[(int)s_list[j]     * 64 + lane];
            float2 v1 = pT2[(int)s_list[j + 1] * 64 + lane];
            float2 v2 = pT2[(int)s_list[j + 2] * 64 + lane];
            float2 v3 = pT2[(int)s_list[j + 3] * 64 + lane];
            float2 v4 = pT2[(int)s_list[j + 4] * 64 + lane];
            float2 v5 = pT2[(int)s_list[j + 5] * 64 + lane];
            float2 v6 = pT2[(int)s_list[j + 6] * 64 + lane];
            float2 v7 = pT2[(int)s_list[j + 7] * 64 + lane];
            x0 += v0.x; y0 += v0.y; x1 += v1.x; y1 += v1.y;
            x2 += v2.x; y2 += v2.y; x3 += v3.x; y3 += v3.y;
            x4 += v4.x; y4 += v4.y; x5 += v5.x; y5 += v5.y;
            x6 += v6.x; y6 += v6.y; x7 += v7.x; y7 += v7.y;
        }
        for (; j < o1; ++j) {
            float2 v = pT2[(int)s_list[j] * 64 + lane];
            x0 += v.x; y0 += v.y;
        }
        float sx = ((x0 + x1) + (x2 + x3)) + ((x4 + x5) + (x6 + x7));
        float sy = ((y0 + y1) + (y2 + y3)) + ((y4 + y5) + (y6 + y7));
        int gbin = a * NR + r;
        if (sx > bv0) { bv0 = sx; bi0 = gbin; }
        if (sy > bv1) { bv1 = sy; bi1 = gbin; }
    }
    s_v0[w][lane] = bv0; s_i0[w][lane] = bi0;
    s_v1[w][lane] = bv1; s_i1[w][lane] = bi1;
    __syncthreads();
    if (w == 0) {
        float m0 = s_v0[0][lane], m1 = s_v1[0][lane];
        int   j0 = s_i0[0][lane], j1 = s_i1[0][lane];
#pragma unroll
        for (int ww = 1; ww < 4; ++ww) {
            float o0v = s_v0[ww][lane]; int o0i = s_i0[ww][lane];
            float o1v = s_v1[ww][lane]; int o1i = s_i1[ww][lane];
            if (o0v > m0 || (o0v == m0 && o0i < j0)) { m0 = o0v; j0 = o0i; }
            if (o1v > m1 || (o1v == m1 && o1i < j1)) { m1 = o1v; j1 = o1i; }
        }
        unsigned long long e0 = ((unsigned long long)__float_as_uint(m0 < 0.f ? 0.f : m0) << 32)
                              | (unsigned long long)(65535 - j0);
        unsigned long long e1 = ((unsigned long long)__float_as_uint(m1 < 0.f ? 0.f : m1) << 32)
                              | (unsigned long long)(65535 - j1);
        atomicMax(&pvp[(2 * lane)     * NA + a], e0);
        atomicMax(&pvp[(2 * lane + 1) * NA + a], e1);
    }
}

// ---------------- Kernel C: final argmax + gather + L1-normalize + loss -----
__global__ __launch_bounds__(64) void loss_kernel(const float* __restrict__ ht,
                                                  const float* __restrict__ pexist,
                                                  const unsigned long long* __restrict__ pvp,
                                                  float* __restrict__ out) {
    const int b = blockIdx.x;
    const int l = threadIdx.x;
    const int p = l >> 2;     // pair 0..15
    const int s = l & 3;      // sub-lane within pair
    const int c = p >> 2;     // channel for ht
    const int k = p & 3;      // channel for idx/exist

    const int bck = b * 4 + k;
    unsigned long long be = 0ull;
    for (int t = 0; t < 15; ++t) {
        int a = s * 15 + t;
        unsigned long long e = pvp[bck * NA + a];
        if (e > be) be = e;
    }
#pragma unroll
    for (int m = 1; m < 4; m <<= 1) {
        unsigned long long oe = __shfl_xor(be, m);
        if (oe > be) be = oe;
    }
    int fidx = 65535 - (int)(be & 0xFFFFull);

    int a0 = fidx / NR;
    int r  = fidx - a0 * NR;
    const float* htc = ht + (size_t)((b * 4 + c) * NA) * NR;

    float acc = 0.0f;
    for (int a = s; a < NA; a += 4) acc += fabsf(htc[a * NR + r]);
    acc += __shfl_xor(acc, 1);
    acc += __shfl_xor(acc, 2);

    float term = 0.0f;
    if (s == 0) {
        float l1 = fmaxf(acc, 1e-12f);
        float gg = htc[a0 * NR + r] / l1;
        float ex = (pexist[b * 4 + k] > 0.9f) ? 1.0f : 0.0f;
        term = -logf(gg + 1e-12f) * ex;
    }
    for (int offt = 32; offt > 0; offt >>= 1) term += __shfl_down(term, offt);
    if (l == 0) out[b] = term * (1.0f / 16.0f);
}

extern "C" void kernel_launch(void* const* d_in, const int* in_sizes, int n_in,
                              void* d_out, int out_size, void* d_ws, size_t ws_size,
                              hipStream_t stream) {
    const float* ht     = (const float*)d_in[0];
    const float* pred   = (const float*)d_in[1];
    const float* pexist = (const float*)d_in[2];
    const float* vote   = (const float*)d_in[3];

    char* ws = (char*)d_ws;
    int*      off    = (int*)     (ws + WS_OFF);
    uint16_t* list   = (uint16_t*)(ws + WS_LIST);
    float*    pred_T = (float*)   (ws + WS_PREDT);
    unsigned long long* pvp = (unsigned long long*)(ws + WS_PVP);

    setup<<<NA + GT_BLKS + ZERO_BLKS, 256, 0, stream>>>(vote, pred, off, list, pred_T, pvp);
    // DIAGNOSTIC: hough_T4 is idempotent (atomicMax, identical operands).
    // Launch 3x to measure its true cost: H = (total - 46.5) / 2.
    hough_T4<<<NA * NSPLIT, 256, 0, stream>>>(pred_T, off, list, pvp);
    hough_T4<<<NA * NSPLIT, 256, 0, stream>>>(pred_T, off, list, pvp);
    hough_T4<<<NA * NSPLIT, 256, 0, stream>>>(pred_T, off, list, pvp);
    loss_kernel<<<NB, 64, 0, stream>>>(ht, pexist, pvp, (float*)d_out);
}

// Round 13
// 38.826 us; speedup vs baseline: 1.8553x; 1.8553x over previous
//
#include <hip/hip_runtime.h>
#include <hip/hip_bf16.h>
#include <stdint.h>
#include <math.h>

#define H_HT 26
#define W_HT 122
#define NPIX (H_HT * W_HT)   // 3172
#define NA 60
#define NR 125
#define NB 32
#define NC 4
#define NBC (NB * NC)        // 128
#define PH 288
#define PW 800
#define NSPLIT 16            // rho splits per angle; wave bins r = q*4+w + 64t
#define PIX_PT 13            // ceil(3172/256) pixels per thread in csr

#define TR_BLKS (H_HT * 8)               // 208 transpose blocks: (h, 16-bc group)
#define ZERO_BLKS 4

// ---- workspace layout (bytes) ----
#define WS_OFF   190336                    // int32 [60*126]          30240
#define WS_LIST  220608                    // uint16[60*3172]        380640
#define WS_PREDT 601280                    // float [3172*128]      1624064
#define WS_PVP   2225344                   // u64   [128*60]          61440

// ---------------- Kernel A: fused setup -------------------------------------
// Blocks [0, NA): per-angle inline rho predict + guarded verify + CSR build.
// Blocks [NA, NA+TR_BLKS): coalesced-row staged transpose into pred_T.
// Last ZERO_BLKS: zero pvp.
__global__ __launch_bounds__(256) void setup(const float* __restrict__ vote,
                                             const float* __restrict__ pred,
                                             int* __restrict__ off,
                                             uint16_t* __restrict__ list,
                                             float* __restrict__ pred_T,
                                             unsigned long long* __restrict__ pvp) {
    const int tid = threadIdx.x;
    if (blockIdx.x < NA) {
        const int a = blockIdx.x;
        __shared__ int s_cnt[NR];
        __shared__ int sc[2][NR];
        __shared__ int s_pre[NR + 1];
        __shared__ int s_cur[NR];

        float sn, cs;
        __sincosf((float)(a * 3) * 0.017453292519943295f, &sn, &cs);

        int  rloc[PIX_PT];
        bool grd[PIX_PT];
#pragma unroll
        for (int k = 0; k < PIX_PT; ++k) {
            int p = tid + k * 256;
            rloc[k] = 0; grd[k] = false;
            if (p < NPIX) {
                int h = p / W_HT;
                int w = p - h * W_HT;
                float xs = (float)w - 60.5f;
                float ys = (float)h - 12.5f;
                float rho = xs * cs + ys * sn;
                int r = (int)rintf(rho) + NR / 2;
                r = r < 0 ? 0 : (r > NR - 1 ? NR - 1 : r);
                rloc[k] = r;
                grd[k] = fabsf(rho - floorf(rho) - 0.5f) < 1e-3f;
            }
        }
        float vv[PIX_PT];
#pragma unroll
        for (int k = 0; k < PIX_PT; ++k) {
            int p = tid + k * 256;
            vv[k] = 1.0f;
            if (p < NPIX && grd[k])
                vv[k] = vote[(size_t)(p * NA + a) * NR + rloc[k]];
        }
#pragma unroll
        for (int k = 0; k < PIX_PT; ++k) {
            int p = tid + k * 256;
            if (p < NPIX && grd[k] && vv[k] == 0.0f) {
                const float* vrow = vote + (size_t)(p * NA + a) * NR;
                int r = rloc[k];
                if (r + 1 < NR && vrow[r + 1] != 0.0f) r = r + 1;
                else if (r - 1 >= 0 && vrow[r - 1] != 0.0f) r = r - 1;
                else {
                    for (int r2 = 0; r2 < NR; ++r2)
                        if (vrow[r2] != 0.0f) { r = r2; break; }
                }
                rloc[k] = r;
            }
        }
        for (int i = tid; i < NR; i += 256) s_cnt[i] = 0;
        __syncthreads();
#pragma unroll
        for (int k = 0; k < PIX_PT; ++k) {
            int p = tid + k * 256;
            if (p < NPIX) atomicAdd(&s_cnt[rloc[k]], 1);
        }
        __syncthreads();
        if (tid < NR) sc[0][tid] = s_cnt[tid];
        __syncthreads();
        int pin = 0;
        for (int d = 1; d < NR; d <<= 1) {
            if (tid < NR) {
                int v = sc[pin][tid];
                if (tid >= d) v += sc[pin][tid - d];
                sc[pin ^ 1][tid] = v;
            }
            __syncthreads();
            pin ^= 1;
        }
        if (tid == 0) s_pre[0] = 0;
        if (tid < NR) s_pre[tid + 1] = sc[pin][tid];
        __syncthreads();
        for (int r = tid; r < NR + 1; r += 256) off[a * (NR + 1) + r] = s_pre[r];
        for (int r = tid; r < NR; r += 256) s_cur[r] = s_pre[r];
        __syncthreads();
#pragma unroll
        for (int k = 0; k < PIX_PT; ++k) {
            int p = tid + k * 256;
            if (p < NPIX) {
                int slot = atomicAdd(&s_cur[rloc[k]], 1);
                list[a * NPIX + slot] = (uint16_t)p;
            }
        }
    } else if (blockIdx.x < NA + TR_BLKS) {
        // staged transpose: block = (h, group of 16 images).
        // Read 16 full rows coalesced (float4), extract 122 sampled cols
        // from LDS (pad 802 -> conflict-light), write 64B-chunked.
        const int bidx = blockIdx.x - NA;
        const int h    = bidx >> 3;        // 0..25
        const int g    = bidx & 7;         // 0..7
        const int bc0  = g * 16;
        __shared__ float s_row[16][802];
        const float C1 = (float)(288.0 / 26.0);
        const float C2 = (float)(800.0 / 122.0);
        const int hi = (int)floorf((float)h * C1);
        for (int i = tid; i < 16 * 200; i += 256) {
            int j  = i / 200;
            int c4 = i - j * 200;
            const float4* rp = reinterpret_cast<const float4*>(
                pred + ((size_t)(bc0 + j) * PH + hi) * PW);
            float4 v = rp[c4];
            s_row[j][c4 * 4 + 0] = v.x;
            s_row[j][c4 * 4 + 1] = v.y;
            s_row[j][c4 * 4 + 2] = v.z;
            s_row[j][c4 * 4 + 3] = v.w;
        }
        __syncthreads();
        for (int idx = tid; idx < W_HT * 16; idx += 256) {
            int w = idx >> 4;              // 0..121
            int j = idx & 15;
            int wi = (int)floorf((float)w * C2);
            pred_T[(size_t)(h * W_HT + w) * NBC + bc0 + j] = s_row[j][wi];
        }
    } else {
        int i0 = (blockIdx.x - NA - TR_BLKS) * 256 + tid;
        for (int i = i0; i < NA * NBC; i += ZERO_BLKS * 256) pvp[i] = 0ull;
    }
}

// ---------------- Kernel B: transposed hough (R10 version, unchanged) -------
__global__ __launch_bounds__(256) void hough_T4(const float* __restrict__ pred_T,
                                                const int* __restrict__ off,
                                                const uint16_t* __restrict__ list,
                                                unsigned long long* __restrict__ pvp) {
    __shared__ uint16_t s_list[NPIX];    // 6344 B
    __shared__ int      s_off[NR + 1];
    __shared__ float    s_v0[4][64], s_v1[4][64];
    __shared__ int      s_i0[4][64], s_i1[4][64];

    const int blk  = blockIdx.x;
    const int a    = blk / NSPLIT;
    const int q    = blk - a * NSPLIT;
    const int tid  = threadIdx.x;
    const int w    = tid >> 6;
    const int lane = tid & 63;

    {   // stage full angle list (coalesced as uint32) + offsets
        const uint32_t* src = reinterpret_cast<const uint32_t*>(list + a * NPIX);
        uint32_t* dst = reinterpret_cast<uint32_t*>(s_list);
        for (int i = tid; i < NPIX / 2; i += 256) dst[i] = src[i];
        for (int r = tid; r < NR + 1; r += 256) s_off[r] = off[a * (NR + 1) + r];
    }
    __syncthreads();

    const float2* pT2 = reinterpret_cast<const float2*>(pred_T);
    float bv0 = -1.0f, bv1 = -1.0f; int bi0 = 0x7fffffff, bi1 = 0x7fffffff;
    for (int r = q * 4 + w; r < NR; r += 64) {
        int o0 = s_off[r];
        int o1 = s_off[r + 1];
        float x0 = 0, x1 = 0, x2 = 0, x3 = 0, x4 = 0, x5 = 0, x6 = 0, x7 = 0;
        float y0 = 0, y1 = 0, y2 = 0, y3 = 0, y4 = 0, y5 = 0, y6 = 0, y7 = 0;
        int j = o0;
        for (; j + 8 <= o1; j += 8) {
            float2 v0 = pT2[(int)s_list[j]     * 64 + lane];
            float2 v1 = pT2[(int)s_list[j + 1] * 64 + lane];
            float2 v2 = pT2[(int)s_list[j + 2] * 64 + lane];
            float2 v3 = pT2[(int)s_list[j + 3] * 64 + lane];
            float2 v4 = pT2[(int)s_list[j + 4] * 64 + lane];
            float2 v5 = pT2[(int)s_list[j + 5] * 64 + lane];
            float2 v6 = pT2[(int)s_list[j + 6] * 64 + lane];
            float2 v7 = pT2[(int)s_list[j + 7] * 64 + lane];
            x0 += v0.x; y0 += v0.y; x1 += v1.x; y1 += v1.y;
            x2 += v2.x; y2 += v2.y; x3 += v3.x; y3 += v3.y;
            x4 += v4.x; y4 += v4.y; x5 += v5.x; y5 += v5.y;
            x6 += v6.x; y6 += v6.y; x7 += v7.x; y7 += v7.y;
        }
        for (; j < o1; ++j) {
            float2 v = pT2[(int)s_list[j] * 64 + lane];
            x0 += v.x; y0 += v.y;
        }
        float sx = ((x0 + x1) + (x2 + x3)) + ((x4 + x5) + (x6 + x7));
        float sy = ((y0 + y1) + (y2 + y3)) + ((y4 + y5) + (y6 + y7));
        int gbin = a * NR + r;
        if (sx > bv0) { bv0 = sx; bi0 = gbin; }
        if (sy > bv1) { bv1 = sy; bi1 = gbin; }
    }
    s_v0[w][lane] = bv0; s_i0[w][lane] = bi0;
    s_v1[w][lane] = bv1; s_i1[w][lane] = bi1;
    __syncthreads();
    if (w == 0) {
        float m0 = s_v0[0][lane], m1 = s_v1[0][lane];
        int   j0 = s_i0[0][lane], j1 = s_i1[0][lane];
#pragma unroll
        for (int ww = 1; ww < 4; ++ww) {
            float o0v = s_v0[ww][lane]; int o0i = s_i0[ww][lane];
            float o1v = s_v1[ww][lane]; int o1i = s_i1[ww][lane];
            if (o0v > m0 || (o0v == m0 && o0i < j0)) { m0 = o0v; j0 = o0i; }
            if (o1v > m1 || (o1v == m1 && o1i < j1)) { m1 = o1v; j1 = o1i; }
        }
        unsigned long long e0 = ((unsigned long long)__float_as_uint(m0 < 0.f ? 0.f : m0) << 32)
                              | (unsigned long long)(65535 - j0);
        unsigned long long e1 = ((unsigned long long)__float_as_uint(m1 < 0.f ? 0.f : m1) << 32)
                              | (unsigned long long)(65535 - j1);
        atomicMax(&pvp[(2 * lane)     * NA + a], e0);
        atomicMax(&pvp[(2 * lane + 1) * NA + a], e1);
    }
}

// ---------------- Kernel C: final argmax + gather + L1-normalize + loss -----
// 256 threads: wave = idx-channel k; lane = c*16 + s. Lane-parallel pvp
// argmax (packed u64 butterfly max); 16-way parallel L1 sum over angles.
// (Validated absmax 0 in round 11.)
__global__ __launch_bounds__(256) void loss4(const float* __restrict__ ht,
                                             const float* __restrict__ pexist,
                                             const unsigned long long* __restrict__ pvp,
                                             float* __restrict__ out) {
    __shared__ float s_sum[4];
    const int b    = blockIdx.x;
    const int tid  = threadIdx.x;
    const int k    = tid >> 6;      // wave = idx/exist channel
    const int lane = tid & 63;
    const int c    = lane >> 4;     // ht channel
    const int s    = lane & 15;

    unsigned long long be = 0ull;
    if (lane < NA) be = pvp[(b * 4 + k) * NA + lane];
#pragma unroll
    for (int m = 32; m > 0; m >>= 1) {
        unsigned long long oe = __shfl_xor(be, m);
        if (oe > be) be = oe;
    }
    int fidx = 65535 - (int)(be & 0xFFFFull);
    int a0 = fidx / NR;
    int r  = fidx - a0 * NR;

    const float* htc = ht + (size_t)((b * 4 + c) * NA) * NR;
    float acc = 0.0f;
#pragma unroll
    for (int t = 0; t < 4; ++t) {
        int a = s + t * 16;
        if (a < NA) acc += fabsf(htc[a * NR + r]);
    }
#pragma unroll
    for (int m = 1; m < 16; m <<= 1) acc += __shfl_xor(acc, m);

    float term = 0.0f;
    if (s == 0) {
        float l1 = fmaxf(acc, 1e-12f);
        float gg = htc[a0 * NR + r] / l1;
        float ex = (pexist[b * 4 + k] > 0.9f) ? 1.0f : 0.0f;
        term = -logf(gg + 1e-12f) * ex;
    }
#pragma unroll
    for (int m = 16; m < 64; m <<= 1) term += __shfl_xor(term, m);
    if (lane == 0) s_sum[k] = term;
    __syncthreads();
    if (tid == 0)
        out[b] = (s_sum[0] + s_sum[1] + s_sum[2] + s_sum[3]) * (1.0f / 16.0f);
}

extern "C" void kernel_launch(void* const* d_in, const int* in_sizes, int n_in,
                              void* d_out, int out_size, void* d_ws, size_t ws_size,
                              hipStream_t stream) {
    const float* ht     = (const float*)d_in[0];
    const float* pred   = (const float*)d_in[1];
    const float* pexist = (const float*)d_in[2];
    const float* vote   = (const float*)d_in[3];

    char* ws = (char*)d_ws;
    int*      off    = (int*)     (ws + WS_OFF);
    uint16_t* list   = (uint16_t*)(ws + WS_LIST);
    float*    pred_T = (float*)   (ws + WS_PREDT);
    unsigned long long* pvp = (unsigned long long*)(ws + WS_PVP);

    setup<<<NA + TR_BLKS + ZERO_BLKS, 256, 0, stream>>>(vote, pred, off, list, pred_T, pvp);
    hough_T4<<<NA * NSPLIT, 256, 0, stream>>>(pred_T, off, list, pvp);
    loss4<<<NB, 256, 0, stream>>>(ht, pexist, pvp, (float*)d_out);
}

// Round 14
// 30.956 us; speedup vs baseline: 2.3270x; 1.2542x over previous
//
#include <hip/hip_runtime.h>
#include <hip/hip_bf16.h>
#include <stdint.h>
#include <math.h>

#define H_HT 26
#define W_HT 122
#define NPIX (H_HT * W_HT)   // 3172
#define NA 60
#define NR 125
#define NB 32
#define NC 4
#define NBC (NB * NC)        // 128
#define PH 288
#define PW 800
#define NSPLIT 16            // rho splits per angle; wave bins r = q*4+w + 64t
#define PIX_PT 13            // ceil(3172/256) pixels per thread in csr

#define TR_BLKS (H_HT * 8)               // 208 transpose blocks: (h, 16-bc group)
#define ZERO_BLKS 4

// ---- workspace layout (bytes) ----
#define WS_OFF   190336                    // int32 [60*126]          30240
#define WS_LIST  220608                    // uint16[60*3172]        380640
#define WS_PREDT 601280                    // float [3172*128]      1624064
#define WS_PVP   2225344                   // u64   [128*60]          61440

// ---------------- Kernel A: fused setup -------------------------------------
// Blocks [0, NA): per-angle EXACT f64 rho predict (numpy op order: mul, mul,
//   add, rint half-even) + CSR build. No vote reads: a=0/a=30 constructed
//   ties are deterministic (cos(0)=1,sin(0)=0 exact; 90deg tie direction set
//   by sign(xs)*6.12e-17, robust to 1-ulp libm differences); non-tie rho sit
//   >=1e-6 from .5 vs <=1e-14 cross-libm error.
// Blocks [NA, NA+TR_BLKS): coalesced-row staged transpose into pred_T.
// Last ZERO_BLKS: zero pvp.
__global__ __launch_bounds__(256) void setup(const float* __restrict__ pred,
                                             int* __restrict__ off,
                                             uint16_t* __restrict__ list,
                                             float* __restrict__ pred_T,
                                             unsigned long long* __restrict__ pvp) {
    const int tid = threadIdx.x;
    if (blockIdx.x < NA) {
        const int a = blockIdx.x;
        __shared__ int s_cnt[NR];
        __shared__ int sc[2][NR];
        __shared__ int s_pre[NR + 1];
        __shared__ int s_cur[NR];

        double t  = __dmul_rn((double)(a * 3), 0.017453292519943295);
        double cs = cos(t);
        double sn = sin(t);

        int rloc[PIX_PT];
#pragma unroll
        for (int k = 0; k < PIX_PT; ++k) {
            int p = tid + k * 256;
            rloc[k] = 0;
            if (p < NPIX) {
                int h = p / W_HT;
                int w = p - h * W_HT;
                double xs = (double)w - 60.5;
                double ys = (double)h - 12.5;
                double rho = __dadd_rn(__dmul_rn(xs, cs), __dmul_rn(ys, sn));
                int r = (int)rint(rho) + NR / 2;
                r = r < 0 ? 0 : (r > NR - 1 ? NR - 1 : r);
                rloc[k] = r;
            }
        }
        for (int i = tid; i < NR; i += 256) s_cnt[i] = 0;
        __syncthreads();
#pragma unroll
        for (int k = 0; k < PIX_PT; ++k) {
            int p = tid + k * 256;
            if (p < NPIX) atomicAdd(&s_cnt[rloc[k]], 1);
        }
        __syncthreads();
        if (tid < NR) sc[0][tid] = s_cnt[tid];
        __syncthreads();
        int pin = 0;
        for (int d = 1; d < NR; d <<= 1) {
            if (tid < NR) {
                int v = sc[pin][tid];
                if (tid >= d) v += sc[pin][tid - d];
                sc[pin ^ 1][tid] = v;
            }
            __syncthreads();
            pin ^= 1;
        }
        if (tid == 0) s_pre[0] = 0;
        if (tid < NR) s_pre[tid + 1] = sc[pin][tid];
        __syncthreads();
        for (int r = tid; r < NR + 1; r += 256) off[a * (NR + 1) + r] = s_pre[r];
        for (int r = tid; r < NR; r += 256) s_cur[r] = s_pre[r];
        __syncthreads();
#pragma unroll
        for (int k = 0; k < PIX_PT; ++k) {
            int p = tid + k * 256;
            if (p < NPIX) {
                int slot = atomicAdd(&s_cur[rloc[k]], 1);
                list[a * NPIX + slot] = (uint16_t)p;
            }
        }
    } else if (blockIdx.x < NA + TR_BLKS) {
        // staged transpose: block = (h, group of 16 images).
        const int bidx = blockIdx.x - NA;
        const int h    = bidx >> 3;        // 0..25
        const int g    = bidx & 7;         // 0..7
        const int bc0  = g * 16;
        __shared__ float s_row[16][802];
        const float C1 = (float)(288.0 / 26.0);
        const float C2 = (float)(800.0 / 122.0);
        const int hi = (int)floorf((float)h * C1);
        for (int i = tid; i < 16 * 200; i += 256) {
            int j  = i / 200;
            int c4 = i - j * 200;
            const float4* rp = reinterpret_cast<const float4*>(
                pred + ((size_t)(bc0 + j) * PH + hi) * PW);
            float4 v = rp[c4];
            s_row[j][c4 * 4 + 0] = v.x;
            s_row[j][c4 * 4 + 1] = v.y;
            s_row[j][c4 * 4 + 2] = v.z;
            s_row[j][c4 * 4 + 3] = v.w;
        }
        __syncthreads();
        for (int idx = tid; idx < W_HT * 16; idx += 256) {
            int w = idx >> 4;              // 0..121
            int j = idx & 15;
            int wi = (int)floorf((float)w * C2);
            pred_T[(size_t)(h * W_HT + w) * NBC + bc0 + j] = s_row[j][wi];
        }
    } else {
        int i0 = (blockIdx.x - NA - TR_BLKS) * 256 + tid;
        for (int i = i0; i < NA * NBC; i += ZERO_BLKS * 256) pvp[i] = 0ull;
    }
}

// ---------------- Kernel B: transposed hough (unchanged, validated) ---------
__global__ __launch_bounds__(256) void hough_T4(const float* __restrict__ pred_T,
                                                const int* __restrict__ off,
                                                const uint16_t* __restrict__ list,
                                                unsigned long long* __restrict__ pvp) {
    __shared__ uint16_t s_list[NPIX];    // 6344 B
    __shared__ int      s_off[NR + 1];
    __shared__ float    s_v0[4][64], s_v1[4][64];
    __shared__ int      s_i0[4][64], s_i1[4][64];

    const int blk  = blockIdx.x;
    const int a    = blk / NSPLIT;
    const int q    = blk - a * NSPLIT;
    const int tid  = threadIdx.x;
    const int w    = tid >> 6;
    const int lane = tid & 63;

    {   // stage full angle list (coalesced as uint32) + offsets
        const uint32_t* src = reinterpret_cast<const uint32_t*>(list + a * NPIX);
        uint32_t* dst = reinterpret_cast<uint32_t*>(s_list);
        for (int i = tid; i < NPIX / 2; i += 256) dst[i] = src[i];
        for (int r = tid; r < NR + 1; r += 256) s_off[r] = off[a * (NR + 1) + r];
    }
    __syncthreads();

    const float2* pT2 = reinterpret_cast<const float2*>(pred_T);
    float bv0 = -1.0f, bv1 = -1.0f; int bi0 = 0x7fffffff, bi1 = 0x7fffffff;
    for (int r = q * 4 + w; r < NR; r += 64) {
        int o0 = s_off[r];
        int o1 = s_off[r + 1];
        float x0 = 0, x1 = 0, x2 = 0, x3 = 0, x4 = 0, x5 = 0, x6 = 0, x7 = 0;
        float y0 = 0, y1 = 0, y2 = 0, y3 = 0, y4 = 0, y5 = 0, y6 = 0, y7 = 0;
        int j = o0;
        for (; j + 8 <= o1; j += 8) {
            float2 v0 = pT2[(int)s_list[j]     * 64 + lane];
            float2 v1 = pT2[(int)s_list[j + 1] * 64 + lane];
            float2 v2 = pT2[(int)s_list[j + 2] * 64 + lane];
            float2 v3 = pT2[(int)s_list[j + 3] * 64 + lane];
            float2 v4 = pT2[(int)s_list[j + 4] * 64 + lane];
            float2 v5 = pT2[(int)s_list[j + 5] * 64 + lane];
            float2 v6 = pT2[(int)s_list[j + 6] * 64 + lane];
            float2 v7 = pT2[(int)s_list[j + 7] * 64 + lane];
            x0 += v0.x; y0 += v0.y; x1 += v1.x; y1 += v1.y;
            x2 += v2.x; y2 += v2.y; x3 += v3.x; y3 += v3.y;
            x4 += v4.x; y4 += v4.y; x5 += v5.x; y5 += v5.y;
            x6 += v6.x; y6 += v6.y; x7 += v7.x; y7 += v7.y;
        }
        for (; j < o1; ++j) {
            float2 v = pT2[(int)s_list[j] * 64 + lane];
            x0 += v.x; y0 += v.y;
        }
        float sx = ((x0 + x1) + (x2 + x3)) + ((x4 + x5) + (x6 + x7));
        float sy = ((y0 + y1) + (y2 + y3)) + ((y4 + y5) + (y6 + y7));
        int gbin = a * NR + r;
        if (sx > bv0) { bv0 = sx; bi0 = gbin; }
        if (sy > bv1) { bv1 = sy; bi1 = gbin; }
    }
    s_v0[w][lane] = bv0; s_i0[w][lane] = bi0;
    s_v1[w][lane] = bv1; s_i1[w][lane] = bi1;
    __syncthreads();
    if (w == 0) {
        float m0 = s_v0[0][lane], m1 = s_v1[0][lane];
        int   j0 = s_i0[0][lane], j1 = s_i1[0][lane];
#pragma unroll
        for (int ww = 1; ww < 4; ++ww) {
            float o0v = s_v0[ww][lane]; int o0i = s_i0[ww][lane];
            float o1v = s_v1[ww][lane]; int o1i = s_i1[ww][lane];
            if (o0v > m0 || (o0v == m0 && o0i < j0)) { m0 = o0v; j0 = o0i; }
            if (o1v > m1 || (o1v == m1 && o1i < j1)) { m1 = o1v; j1 = o1i; }
        }
        unsigned long long e0 = ((unsigned long long)__float_as_uint(m0 < 0.f ? 0.f : m0) << 32)
                              | (unsigned long long)(65535 - j0);
        unsigned long long e1 = ((unsigned long long)__float_as_uint(m1 < 0.f ? 0.f : m1) << 32)
                              | (unsigned long long)(65535 - j1);
        atomicMax(&pvp[(2 * lane)     * NA + a], e0);
        atomicMax(&pvp[(2 * lane + 1) * NA + a], e1);
    }
}

// ---------------- Kernel C: final argmax + gather + L1-normalize + loss -----
__global__ __launch_bounds__(256) void loss4(const float* __restrict__ ht,
                                             const float* __restrict__ pexist,
                                             const unsigned long long* __restrict__ pvp,
                                             float* __restrict__ out) {
    __shared__ float s_sum[4];
    const int b    = blockIdx.x;
    const int tid  = threadIdx.x;
    const int k    = tid >> 6;      // wave = idx/exist channel
    const int lane = tid & 63;
    const int c    = lane >> 4;     // ht channel
    const int s    = lane & 15;

    unsigned long long be = 0ull;
    if (lane < NA) be = pvp[(b * 4 + k) * NA + lane];
#pragma unroll
    for (int m = 32; m > 0; m >>= 1) {
        unsigned long long oe = __shfl_xor(be, m);
        if (oe > be) be = oe;
    }
    int fidx = 65535 - (int)(be & 0xFFFFull);
    int a0 = fidx / NR;
    int r  = fidx - a0 * NR;

    const float* htc = ht + (size_t)((b * 4 + c) * NA) * NR;
    float acc = 0.0f;
#pragma unroll
    for (int t = 0; t < 4; ++t) {
        int a = s + t * 16;
        if (a < NA) acc += fabsf(htc[a * NR + r]);
    }
#pragma unroll
    for (int m = 1; m < 16; m <<= 1) acc += __shfl_xor(acc, m);

    float term = 0.0f;
    if (s == 0) {
        float l1 = fmaxf(acc, 1e-12f);
        float gg = htc[a0 * NR + r] / l1;
        float ex = (pexist[b * 4 + k] > 0.9f) ? 1.0f : 0.0f;
        term = -logf(gg + 1e-12f) * ex;
    }
#pragma unroll
    for (int m = 16; m < 64; m <<= 1) term += __shfl_xor(term, m);
    if (lane == 0) s_sum[k] = term;
    __syncthreads();
    if (tid == 0)
        out[b] = (s_sum[0] + s_sum[1] + s_sum[2] + s_sum[3]) * (1.0f / 16.0f);
}

extern "C" void kernel_launch(void* const* d_in, const int* in_sizes, int n_in,
                              void* d_out, int out_size, void* d_ws, size_t ws_size,
                              hipStream_t stream) {
    const float* ht     = (const float*)d_in[0];
    const float* pred   = (const float*)d_in[1];
    const float* pexist = (const float*)d_in[2];

    char* ws = (char*)d_ws;
    int*      off    = (int*)     (ws + WS_OFF);
    uint16_t* list   = (uint16_t*)(ws + WS_LIST);
    float*    pred_T = (float*)   (ws + WS_PREDT);
    unsigned long long* pvp = (unsigned long long*)(ws + WS_PVP);

    setup<<<NA + TR_BLKS + ZERO_BLKS, 256, 0, stream>>>(pred, off, list, pred_T, pvp);
    hough_T4<<<NA * NSPLIT, 256, 0, stream>>>(pred_T, off, list, pvp);
    loss4<<<NB, 256, 0, stream>>>(ht, pexist, pvp, (float*)d_out);
}